// Round 2
// baseline (2074.223 us; speedup 1.0000x reference)
//
#include <hip/hip_runtime.h>
#include <cmath>
#include <cstring>
#include <mutex>
#include <algorithm>

#ifndef M_PI
#define M_PI 3.14159265358979323846
#endif

// ---------------- problem constants ----------------
// B_IN=32, B_OUT=16, BATCH=32, F_IN=64, F_OUT=32, GRID=24
// lm index: l*l + (m+l), l=0..15, m=-l..l  -> 256
// l-major pack (k_fz): off_l + (m+l)*(2l+1)+(n+l), off_l = l(4l^2-1)/3 -> 5456
// mn-major pack (k_synth): per (m,n) runs over l=lmin..15, run base mn_off[t],
//   t = (m+15)*31 + (n+15); run len = 16-max(|m|,|n|)
#define NLM   256
#define NPACK 5456
#define NMN   961   // 31*31 (m,n) pairs

struct Tables {
  float WtT[64 * NLM];    // [beta_in b][lm] : w[b]*d^l_{m,0}(beta_b)  (transposed for coalescing)
  float Yre[24 * NLM];    // [g][lm]
  float Yim[24 * NLM];
  float Dp[32 * NPACK];   // [b][mn-packed l-runs] : (2l+1)*d^l_{m,n}(beta_out_b)
  float c64[64], s64[64]; // cos/sin(2pi t/64)
  float c32[32], s32[32];
  int   mn_off[NMN];      // run offset per (m,n)
  int   qmap[NPACK];      // mn-packed index q -> l-major pack index p
};

__constant__ int d_off[17] = {0,1,10,35,84,165,286,455,680,969,1330,1771,
                              2300,2925,3654,4495,5456};

// ---------------- host-side table construction (f64 -> f32, matches reference) ----
static void h_wigner(int l, double beta, double* d) { // (2l+1)^2, row i=mp+l, col j=mm+l
  double cb = std::cos(beta * 0.5), sb = std::sin(beta * 0.5);
  int L = 2 * l + 1;
  for (int i = 0; i < L; i++) {
    int mp = i - l;
    for (int j = 0; j < L; j++) {
      int mm = j - l;
      double pref = 0.5 * (std::lgamma(l + mp + 1.0) + std::lgamma(l - mp + 1.0) +
                           std::lgamma(l + mm + 1.0) + std::lgamma(l - mm + 1.0));
      double tot = 0.0;
      int s0 = std::max(0, mm - mp), s1 = std::min(l + mm, l - mp);
      for (int s = s0; s <= s1; s++) {
        double ln = pref - (std::lgamma(l + mm - s + 1.0) + std::lgamma(s + 1.0) +
                            std::lgamma(mp - mm + s + 1.0) + std::lgamma(l - mp - s + 1.0));
        double term = std::exp(ln) * std::pow(cb, (double)(2 * l + mm - mp - 2 * s)) *
                      std::pow(sb, (double)(mp - mm + 2 * s));
        tot += ((mp - mm + s) & 1) ? -term : term;
      }
      d[i * L + j] = tot;
    }
  }
}

static void build_tables(Tables& T) {
  double dbuf[31 * 31];
  double w[64];
  for (int j = 0; j < 64; j++) {
    double s = 0.0;
    for (int k = 0; k < 32; k++)
      s += std::sin((2.0 * j + 1.0) * (2.0 * k + 1.0) * M_PI / 128.0) / (2.0 * k + 1.0);
    w[j] = (2.0 / 32.0) * std::sin(M_PI * (2.0 * j + 1.0) / 128.0) * s * (2.0 * M_PI / 4096.0);
  }
  for (int j = 0; j < 64; j++) {
    double beta = M_PI * (2.0 * j + 1.0) / 128.0;
    for (int l = 0; l < 16; l++) {
      int L = 2 * l + 1;
      h_wigner(l, beta, dbuf);
      for (int i = 0; i < L; i++)
        T.WtT[j * NLM + (l * l + i)] = (float)(w[j] * dbuf[i * L + l]); // column mm=0
    }
  }
  for (int bi = 0; bi < 3; bi++) {
    double beta = (bi + 1) * M_PI / 24.0;
    for (int l = 0; l < 16; l++) {
      int L = 2 * l + 1;
      h_wigner(l, beta, dbuf);
      double coef = std::sqrt((2.0 * l + 1.0) / (4.0 * M_PI));
      for (int ai = 0; ai < 8; ai++) {
        double alpha = ai * M_PI / 4.0;
        int g = bi * 8 + ai;
        for (int i = 0; i < L; i++) {
          int m = i - l;
          double v = coef * dbuf[i * L + l];
          T.Yre[g * NLM + l * l + i] = (float)(v * std::cos(m * alpha));
          T.Yim[g * NLM + l * l + i] = (float)(v * std::sin(m * alpha));
        }
      }
    }
  }
  {
    int acc = 0;
    for (int t = 0; t < NMN; t++) {
      int m = t / 31 - 15, n = t % 31 - 15;
      int lmin = std::max(std::abs(m), std::abs(n));
      T.mn_off[t] = acc;
      acc += 16 - lmin;
    }
  }
  // Dp[b][packed] and qmap (mn-packed q -> l-major p)
  for (int b = 0; b < 32; b++) {
    double beta = M_PI * (2.0 * b + 1.0) / 64.0;
    for (int l = 0; l < 16; l++) {
      int L = 2 * l + 1;
      h_wigner(l, beta, dbuf);
      for (int i = 0; i < L; i++)
        for (int j = 0; j < L; j++) {
          int m = i - l, n = j - l;
          int t = (m + 15) * 31 + (n + 15);
          int lmin = std::max(std::abs(m), std::abs(n));
          int q = T.mn_off[t] + (l - lmin);
          T.Dp[b * NPACK + q] = (float)((2.0 * l + 1.0) * dbuf[i * L + j]);
          if (b == 0) {
            int p = (l * (4 * l * l - 1)) / 3 + (m + l) * (2 * l + 1) + (n + l);
            T.qmap[q] = p;
          }
        }
    }
  }
  for (int t = 0; t < 64; t++) {
    T.c64[t] = (float)std::cos(2.0 * M_PI * t / 64.0);
    T.s64[t] = (float)std::sin(2.0 * M_PI * t / 64.0);
  }
  for (int t = 0; t < 32; t++) {
    T.c32[t] = (float)std::cos(2.0 * M_PI * t / 32.0);
    T.s32[t] = (float)std::sin(2.0 * M_PI * t / 32.0);
  }
}

// ---------------- kernels ----------------

// K1: fused alpha-DFT (31 bins) + beta contraction.  One block per (z,f).
// x: [32 z][64 f][64 b][64 a] f32 ;  z_arr: [256 lm][32 z * 64 f] c64
__global__ __launch_bounds__(256) void k_zbuild(const float* __restrict__ x,
                                                const float* __restrict__ WtT,
                                                const float* __restrict__ tc,
                                                const float* __restrict__ ts,
                                                float2* __restrict__ z_arr) {
  __shared__ float xr[4096];
  __shared__ __align__(16) float2 fz2[64 * 32]; // [b][mi], mi stride 32
  __shared__ float lc[64], ls[64];
  int zf = blockIdx.x, tid = threadIdx.x;
  if (tid < 64) { lc[tid] = tc[tid]; ls[tid] = ts[tid]; }
  const float4* xp4 = (const float4*)(x + (size_t)zf * 4096);
  float4* xr4 = (float4*)xr;
  for (int i = tid; i < 1024; i += 256) xr4[i] = xp4[i];
  __syncthreads();
  // phase A: thread (mi = tid&31, r = tid>>5) handles b = r+8k, k=0..7
  {
    int mi = tid & 31, r = tid >> 5;
    int m = mi - 15, mm = m & 63;
    float re[8], im[8];
#pragma unroll
    for (int k2 = 0; k2 < 8; k2++) { re[k2] = 0.f; im[k2] = 0.f; }
    int t = 0; // (m*a) & 63, exact incremental
    for (int a = 0; a < 64; a++) {
      float cw = lc[t], sw = ls[t];
#pragma unroll
      for (int k2 = 0; k2 < 8; k2++) {
        float v = xr[(r + 8 * k2) * 64 + a];
        re[k2] += v * cw;
        im[k2] -= v * sw;
      }
      t = (t + mm) & 63;
    }
    if (mi < 31) {
#pragma unroll
      for (int k2 = 0; k2 < 8; k2++)
        fz2[(r + 8 * k2) * 32 + mi] = make_float2(re[k2], im[k2]);
    }
  }
  __syncthreads();
  // phase C: z[lm] = sum_b WtT[b][lm] * xf[b][mi(lm)]
  {
    int lm = tid;
    int l = (int)sqrtf((float)lm + 0.5f);
    if (l * l > lm) l--;
    else if ((l + 1) * (l + 1) <= lm) l++;
    int miC = (lm - l * l) - l + 15;
    float zr = 0.f, zi = 0.f;
    for (int b = 0; b < 64; b++) {
      float wv = WtT[b * NLM + lm];
      float2 f = fz2[b * 32 + miC];
      zr += wv * f.x;
      zi += wv * f.y;
    }
    z_arr[(size_t)lm * 2048 + zf] = make_float2(zr, zi);
  }
}

// K2: y[lm][f][o] = sum_g (kernel[f][o][g]*S) * Y[g][lm].  One block per lm.
__global__ __launch_bounds__(256) void k_ybuild(const float* __restrict__ kern,
                                                const float* __restrict__ Yre,
                                                const float* __restrict__ Yim,
                                                float S, float2* __restrict__ y_arr) {
  __shared__ float yr[24], yi[24];
  int lm = blockIdx.x, tid = threadIdx.x;
  if (tid < 24) { yr[tid] = Yre[tid * NLM + lm]; yi[tid] = Yim[tid * NLM + lm]; }
  __syncthreads();
  for (int p = tid; p < 2048; p += 256) {
    const float* kp = kern + (size_t)p * 24;
    float re = 0.f, im = 0.f;
    for (int g = 0; g < 24; g++) {
      float kv = kp[g] * S;
      re += kv * yr[g];
      im += kv * yi[g];
    }
    y_arr[(size_t)lm * 2048 + p] = make_float2(re, im);
  }
}

// K3: per (l,m1,m2): num = sum_f z1*y2 (c64), den = Re sum_f conj(y1)*y2 (f64 acc),
//     Fz = num/den. One block per l-major pack. Writes Fz [pack][z32*o32] c64.
__global__ __launch_bounds__(256) void k_fz(const float2* __restrict__ z_arr,
                                            const float2* __restrict__ y_arr,
                                            float2* __restrict__ fz) {
  __shared__ __align__(16) float2 z1[2048];   // [zz][f]
  __shared__ __align__(16) float2 y1s[2048];  // [f][o]
  __shared__ __align__(16) float2 y2s[2048];  // [f][o]
  int pack = blockIdx.x, tid = threadIdx.x;
  int l = 15;
  while (d_off[l] > pack) l--;
  int rr = pack - d_off[l];
  int L = 2 * l + 1;
  int i1 = rr / L, i2 = rr - i1 * L;
  int lm1 = l * l + i1, lm2 = l * l + i2;
  for (int i = tid; i < 2048; i += 256) {
    z1[i]  = z_arr[(size_t)lm1 * 2048 + i];
    y1s[i] = y_arr[(size_t)lm1 * 2048 + i];
    y2s[i] = y_arr[(size_t)lm2 * 2048 + i];
  }
  __syncthreads();
  int zz = tid >> 3, oq = tid & 7; // 4 outputs: oo = 4*oq + 0..3
  float nr0 = 0.f, ni0 = 0.f, nr1 = 0.f, ni1 = 0.f;
  float nr2 = 0.f, ni2 = 0.f, nr3 = 0.f, ni3 = 0.f;
  double d0 = 0.0, d1 = 0.0, d2 = 0.0, d3 = 0.0;
  const float2* z1p = &z1[zz * 64];
  for (int f = 0; f < 64; f++) {
    float2 a = z1p[f];
    float2 c = y1s[f * 32 + zz];
    float4 b01 = *(const float4*)&y2s[f * 32 + 4 * oq];
    float4 b23 = *(const float4*)&y2s[f * 32 + 4 * oq + 2];
    nr0 += a.x * b01.x - a.y * b01.y;  ni0 += a.x * b01.y + a.y * b01.x;
    nr1 += a.x * b01.z - a.y * b01.w;  ni1 += a.x * b01.w + a.y * b01.z;
    nr2 += a.x * b23.x - a.y * b23.y;  ni2 += a.x * b23.y + a.y * b23.x;
    nr3 += a.x * b23.z - a.y * b23.w;  ni3 += a.x * b23.w + a.y * b23.z;
    d0 += (double)c.x * (double)b01.x + (double)c.y * (double)b01.y;
    d1 += (double)c.x * (double)b01.z + (double)c.y * (double)b01.w;
    d2 += (double)c.x * (double)b23.x + (double)c.y * (double)b23.y;
    d3 += (double)c.x * (double)b23.z + (double)c.y * (double)b23.w;
  }
  size_t base = (size_t)pack * 1024 + zz * 32 + 4 * oq;
  fz[base + 0] = make_float2(nr0 / (float)d0, ni0 / (float)d0);
  fz[base + 1] = make_float2(nr1 / (float)d1, ni1 / (float)d1);
  fz[base + 2] = make_float2(nr2 / (float)d2, ni2 / (float)d2);
  fz[base + 3] = make_float2(nr3 / (float)d3, ni3 / (float)d3);
}

// K4: permuting transpose: xt[zo][q] = fz[qmap[q]][zo]   (both c64), tiled.
__global__ __launch_bounds__(256) void k_tr(const float2* __restrict__ fz,
                                            const int* __restrict__ qmap,
                                            float2* __restrict__ xt) {
  __shared__ float2 tile[32][33];
  __shared__ int qm[32];
  int zo0 = blockIdx.x * 32;  // 0..1023
  int q0 = blockIdx.y * 32;   // 0..5455
  int tid = threadIdx.x;
  int c = tid & 31, r0 = tid >> 5;
  if (tid < 32) qm[tid] = (q0 + tid < NPACK) ? qmap[q0 + tid] : -1;
  __syncthreads();
  for (int r = r0; r < 32; r += 8) {
    int p = qm[r];
    if (p >= 0) tile[r][c] = fz[(size_t)p * 1024 + zo0 + c];
  }
  __syncthreads();
  for (int r = r0; r < 32; r += 8) {
    if (q0 + c < NPACK)
      xt[(size_t)(zo0 + r) * NPACK + q0 + c] = tile[c][r];
  }
}

// K5: synthesis. Grid 2048: zo = bx>>1, b-range = 16 per block.
// Per b: F[mi,ni] = sum_l X[packed]*D_b[packed]; 31x31 -> 32x32 inverse 2D Fourier (Re).
__global__ __launch_bounds__(256, 4) void k_synth(const float2* __restrict__ xt,
                                                  const float* __restrict__ Dp,
                                                  const int* __restrict__ mn_off,
                                                  const float* __restrict__ gc32,
                                                  const float* __restrict__ gs32,
                                                  const float* __restrict__ bias,
                                                  float* __restrict__ out) {
  __shared__ __align__(16) float2 F2T[31 * 32];  // [ni][mi], mi stride 32
  __shared__ __align__(16) float2 G2[31 * 32];   // [mi][kk]
  __shared__ __align__(16) float2 tw2[32 * 31];  // [k][ni] : e^{2pi i k(ni-15)/32}, exact
  int bx = blockIdx.x, tid = threadIdx.x;
  int zo = bx >> 1;
  int b0 = (bx & 1) * 16, b1 = b0 + 16;
  int kk = tid & 31, row = tid >> 5; // row 0..7

  // exact twiddle table from global cos/sin tables
  for (int i = tid; i < 992; i += 256) {
    int kq = i / 31, nq = i - 31 * kq;
    int p = (kq * (nq - 15)) & 31;
    tw2[i] = make_float2(gc32[p], gs32[p]);
  }
  if (tid < 31) F2T[tid * 32 + 31] = make_float2(0.f, 0.f); // unused column

  // per-thread F-build slots: t = tid + 256*s over 961 (m,n) pairs
  int xb[4], ln[4], wo[4];
#pragma unroll
  for (int s = 0; s < 4; s++) {
    int t = tid + 256 * s;
    if (t < NMN) {
      int mi = t / 31, ni = t - 31 * mi;
      int m = mi - 15, n = ni - 15;
      int am = m < 0 ? -m : m, an = n < 0 ? -n : n;
      int lmin = am > an ? am : an;
      xb[s] = mn_off[t];
      ln[s] = 16 - lmin;
      wo[s] = ni * 32 + mi;
    } else {
      xb[s] = 0; ln[s] = 0; wo[s] = 0;
    }
  }
  const float2* Xrow = xt + (size_t)zo * NPACK;
  float bv = bias[zo & 31];

  // F-build for first b
  {
    const float* Db = Dp + (size_t)b0 * NPACK;
#pragma unroll
    for (int s = 0; s < 4; s++) {
      int L = ln[s];
      if (L > 0) {
        const float2* xp = Xrow + xb[s];
        const float* dp = Db + xb[s];
        float fr = 0.f, fi = 0.f;
        for (int li = 0; li < L; li++) {
          float2 xv = xp[li];
          float dv = dp[li];
          fr += xv.x * dv;
          fi += xv.y * dv;
        }
        F2T[wo[s]] = make_float2(fr, fi);
      }
    }
  }
  __syncthreads();

  for (int b = b0; b < b1; b++) {
    // ---- stage 1: G[mi,kk] = sum_ni F[mi,ni] e^{2pi i kk(ni-15)/32}
    {
      float gr0 = 0.f, gi0 = 0.f, gr1 = 0.f, gi1 = 0.f;
      float gr2 = 0.f, gi2 = 0.f, gr3 = 0.f, gi3 = 0.f;
      int m0 = 2 * row;            // mi pair A: m0, m0+1
      int m1 = 2 * row + 16;       // mi pair B: m1, m1+1 (m1+1==31 unused for row 7)
#pragma unroll
      for (int ni = 0; ni < 31; ni++) {
        float4 fa = *(const float4*)&F2T[ni * 32 + m0];
        float4 fb = *(const float4*)&F2T[ni * 32 + m1];
        float2 w = tw2[kk * 31 + ni];
        gr0 += fa.x * w.x - fa.y * w.y;  gi0 += fa.x * w.y + fa.y * w.x;
        gr1 += fa.z * w.x - fa.w * w.y;  gi1 += fa.z * w.y + fa.w * w.x;
        gr2 += fb.x * w.x - fb.y * w.y;  gi2 += fb.x * w.y + fb.y * w.x;
        gr3 += fb.z * w.x - fb.w * w.y;  gi3 += fb.z * w.y + fb.w * w.x;
      }
      G2[m0 * 32 + kk] = make_float2(gr0, gi0);
      G2[(m0 + 1) * 32 + kk] = make_float2(gr1, gi1);
      G2[m1 * 32 + kk] = make_float2(gr2, gi2);
      if (m1 + 1 < 31) G2[(m1 + 1) * 32 + kk] = make_float2(gr3, gi3);
    }
    __syncthreads();

    // ---- F-build for next b (overlaps stage 2)
    if (b + 1 < b1) {
      const float* Db = Dp + (size_t)(b + 1) * NPACK;
#pragma unroll
      for (int s = 0; s < 4; s++) {
        int L = ln[s];
        if (L > 0) {
          const float2* xp = Xrow + xb[s];
          const float* dp = Db + xb[s];
          float fr = 0.f, fi = 0.f;
          for (int li = 0; li < L; li++) {
            float2 xv = xp[li];
            float dv = dp[li];
            fr += xv.x * dv;
            fi += xv.y * dv;
          }
          F2T[wo[s]] = make_float2(fr, fi);
        }
      }
    }

    // ---- stage 2: out[j,kk] = Re sum_mi G[mi,kk] e^{2pi i j(mi-15)/32},
    //      j = row + 8s, using e^{i pi s(mi-15)/2} = i^{s(mi-15)} sign folding
    {
      float acc0 = 0.f, acc1 = 0.f, acc2 = 0.f, acc3 = 0.f;
#pragma unroll
      for (int mi = 0; mi < 31; mi++) {
        float2 g = G2[mi * 32 + kk];
        float2 w = tw2[row * 31 + mi];
        float u = g.x * w.x - g.y * w.y;   // Re(G*w)
        float v = g.x * w.y + g.y * w.x;   // Im(G*w)
        acc0 += u;
        {
          constexpr int dummy = 0; (void)dummy;
        }
        int p1 = (1 * (mi - 15)) & 3;
        int p2 = (2 * (mi - 15)) & 3;
        int p3 = (3 * (mi - 15)) & 3;
        acc1 += (p1 == 0) ? u : (p1 == 1) ? -v : (p1 == 2) ? -u : v;
        acc2 += (p2 == 0) ? u : (p2 == 1) ? -v : (p2 == 2) ? -u : v;
        acc3 += (p3 == 0) ? u : (p3 == 1) ? -v : (p3 == 2) ? -u : v;
      }
      size_t base = (size_t)zo * 32768 + (size_t)b * 1024 + kk;
      out[base + (row + 0) * 32]  = acc0 + bv;
      out[base + (row + 8) * 32]  = acc1 + bv;
      out[base + (row + 16) * 32] = acc2 + bv;
      out[base + (row + 24) * 32] = acc3 + bv;
    }
    __syncthreads();
  }
}

// ---------------- launch ----------------
static Tables* g_htbl = nullptr;
static std::once_flag g_once;

static constexpr size_t align256(size_t v) { return (v + 255) & ~(size_t)255; }
static constexpr size_t WS_TBL = 0;
static constexpr size_t WS_Z   = align256(sizeof(Tables));
static constexpr size_t WS_Y   = WS_Z + (size_t)NLM * 2048 * 8;
static constexpr size_t WS_FZ  = WS_Y + (size_t)NLM * 2048 * 8;
static constexpr size_t WS_XT  = WS_FZ + (size_t)NPACK * 1024 * 8;

extern "C" void kernel_launch(void* const* d_in, const int* in_sizes, int n_in,
                              void* d_out, int out_size, void* d_ws, size_t ws_size,
                              hipStream_t stream) {
  std::call_once(g_once, [] {
    hipHostMalloc((void**)&g_htbl, sizeof(Tables));
    build_tables(*g_htbl);
  });

  const float* x = (const float*)d_in[0];
  const float* kern = (const float*)d_in[1];
  const float* bias = (const float*)d_in[2];
  float* out = (float*)d_out;
  char* ws = (char*)d_ws;

  hipMemcpyAsync(ws + WS_TBL, g_htbl, sizeof(Tables), hipMemcpyHostToDevice, stream);

  Tables* dT = (Tables*)(ws + WS_TBL);
  float2* z_arr = (float2*)(ws + WS_Z);
  float2* y_arr = (float2*)(ws + WS_Y);
  float2* fzb   = (float2*)(ws + WS_FZ);
  float2* xtb   = (float2*)(ws + WS_XT);

  float S = (float)(1.0 / std::sqrt(24.0 * 64.0 * 65536.0 / 1024.0));

  k_zbuild<<<2048, 256, 0, stream>>>(x, dT->WtT, dT->c64, dT->s64, z_arr);
  k_ybuild<<<256, 256, 0, stream>>>(kern, dT->Yre, dT->Yim, S, y_arr);
  k_fz<<<NPACK, 256, 0, stream>>>(z_arr, y_arr, fzb);
  k_tr<<<dim3(32, 171), 256, 0, stream>>>(fzb, dT->qmap, xtb);
  k_synth<<<2048, 256, 0, stream>>>(xtb, dT->Dp, dT->mn_off, dT->c32, dT->s32, bias, out);
}

// Round 3
// 756.645 us; speedup vs baseline: 2.7413x; 2.7413x over previous
//
#include <hip/hip_runtime.h>
#include <cmath>
#include <cstring>
#include <mutex>
#include <algorithm>

#ifndef M_PI
#define M_PI 3.14159265358979323846
#endif

// ---------------- problem constants ----------------
// B_IN=32, B_OUT=16, BATCH=32, F_IN=64, F_OUT=32, GRID=24
// lm index: l*l + (m+l), l=0..15, m=-l..l  -> 256
// l-major pack (k_fz): off_l + (m+l)*(2l+1)+(n+l), off_l = l(4l^2-1)/3 -> 5456
// mn-major pack (k_synth): per (m,n) runs over l=lmin..15, run base mn_off[t],
//   t = (m+15)*31 + (n+15); run len = 16-max(|m|,|n|)
#define NLM   256
#define NPACK 5456
#define NMN   961   // 31*31 (m,n) pairs

struct Tables {
  float WtT[64 * NLM];    // [beta_in b][lm] : w[b]*d^l_{m,0}(beta_b)
  float Yre[24 * NLM];    // [g][lm]
  float Yim[24 * NLM];
  float Dp[32 * NPACK];   // [b][mn-packed l-runs] : (2l+1)*d^l_{m,n}(beta_out_b)
  float c64[64], s64[64]; // cos/sin(2pi t/64)
  float c32[32], s32[32];
  int   mn_off[NMN];      // run offset per (m,n)
  int   qmap[NPACK];      // mn-packed index q -> l-major pack index p
};

__constant__ int d_off[17] = {0,1,10,35,84,165,286,455,680,969,1330,1771,
                              2300,2925,3654,4495,5456};

// ---------------- host-side table construction (f64 -> f32, matches reference) ----
static void h_wigner(int l, double beta, double* d) { // (2l+1)^2, row i=mp+l, col j=mm+l
  double cb = std::cos(beta * 0.5), sb = std::sin(beta * 0.5);
  int L = 2 * l + 1;
  for (int i = 0; i < L; i++) {
    int mp = i - l;
    for (int j = 0; j < L; j++) {
      int mm = j - l;
      double pref = 0.5 * (std::lgamma(l + mp + 1.0) + std::lgamma(l - mp + 1.0) +
                           std::lgamma(l + mm + 1.0) + std::lgamma(l - mm + 1.0));
      double tot = 0.0;
      int s0 = std::max(0, mm - mp), s1 = std::min(l + mm, l - mp);
      for (int s = s0; s <= s1; s++) {
        double ln = pref - (std::lgamma(l + mm - s + 1.0) + std::lgamma(s + 1.0) +
                            std::lgamma(mp - mm + s + 1.0) + std::lgamma(l - mp - s + 1.0));
        double term = std::exp(ln) * std::pow(cb, (double)(2 * l + mm - mp - 2 * s)) *
                      std::pow(sb, (double)(mp - mm + 2 * s));
        tot += ((mp - mm + s) & 1) ? -term : term;
      }
      d[i * L + j] = tot;
    }
  }
}

static void build_tables(Tables& T) {
  double dbuf[31 * 31];
  double w[64];
  for (int j = 0; j < 64; j++) {
    double s = 0.0;
    for (int k = 0; k < 32; k++)
      s += std::sin((2.0 * j + 1.0) * (2.0 * k + 1.0) * M_PI / 128.0) / (2.0 * k + 1.0);
    w[j] = (2.0 / 32.0) * std::sin(M_PI * (2.0 * j + 1.0) / 128.0) * s * (2.0 * M_PI / 4096.0);
  }
  for (int j = 0; j < 64; j++) {
    double beta = M_PI * (2.0 * j + 1.0) / 128.0;
    for (int l = 0; l < 16; l++) {
      int L = 2 * l + 1;
      h_wigner(l, beta, dbuf);
      for (int i = 0; i < L; i++)
        T.WtT[j * NLM + (l * l + i)] = (float)(w[j] * dbuf[i * L + l]); // column mm=0
    }
  }
  for (int bi = 0; bi < 3; bi++) {
    double beta = (bi + 1) * M_PI / 24.0;
    for (int l = 0; l < 16; l++) {
      int L = 2 * l + 1;
      h_wigner(l, beta, dbuf);
      double coef = std::sqrt((2.0 * l + 1.0) / (4.0 * M_PI));
      for (int ai = 0; ai < 8; ai++) {
        double alpha = ai * M_PI / 4.0;
        int g = bi * 8 + ai;
        for (int i = 0; i < L; i++) {
          int m = i - l;
          double v = coef * dbuf[i * L + l];
          T.Yre[g * NLM + l * l + i] = (float)(v * std::cos(m * alpha));
          T.Yim[g * NLM + l * l + i] = (float)(v * std::sin(m * alpha));
        }
      }
    }
  }
  {
    int acc = 0;
    for (int t = 0; t < NMN; t++) {
      int m = t / 31 - 15, n = t % 31 - 15;
      int lmin = std::max(std::abs(m), std::abs(n));
      T.mn_off[t] = acc;
      acc += 16 - lmin;
    }
  }
  // Dp[b][packed] and qmap (mn-packed q -> l-major p)
  for (int b = 0; b < 32; b++) {
    double beta = M_PI * (2.0 * b + 1.0) / 64.0;
    for (int l = 0; l < 16; l++) {
      int L = 2 * l + 1;
      h_wigner(l, beta, dbuf);
      for (int i = 0; i < L; i++)
        for (int j = 0; j < L; j++) {
          int m = i - l, n = j - l;
          int t = (m + 15) * 31 + (n + 15);
          int lmin = std::max(std::abs(m), std::abs(n));
          int q = T.mn_off[t] + (l - lmin);
          T.Dp[b * NPACK + q] = (float)((2.0 * l + 1.0) * dbuf[i * L + j]);
          if (b == 0) {
            int p = (l * (4 * l * l - 1)) / 3 + (m + l) * (2 * l + 1) + (n + l);
            T.qmap[q] = p;
          }
        }
    }
  }
  for (int t = 0; t < 64; t++) {
    T.c64[t] = (float)std::cos(2.0 * M_PI * t / 64.0);
    T.s64[t] = (float)std::sin(2.0 * M_PI * t / 64.0);
  }
  for (int t = 0; t < 32; t++) {
    T.c32[t] = (float)std::cos(2.0 * M_PI * t / 32.0);
    T.s32[t] = (float)std::sin(2.0 * M_PI * t / 32.0);
  }
}

// ---------------- kernels ----------------

// K1: fused alpha-DFT (31 bins) + beta contraction.  One block per (z,f).
// x: [32 z][64 f][64 b][64 a] f32 ;  z_arr: [256 lm][32 z * 64 f] c64
__global__ __launch_bounds__(256) void k_zbuild(const float* __restrict__ x,
                                                const float* __restrict__ WtT,
                                                const float* __restrict__ tc,
                                                const float* __restrict__ ts,
                                                float2* __restrict__ z_arr) {
  __shared__ float xr[4096];
  __shared__ __align__(16) float2 fz2[64 * 32]; // [b][mi], mi stride 32
  __shared__ float lc[64], ls[64];
  int zf = blockIdx.x, tid = threadIdx.x;
  if (tid < 64) { lc[tid] = tc[tid]; ls[tid] = ts[tid]; }
  const float4* xp4 = (const float4*)(x + (size_t)zf * 4096);
  float4* xr4 = (float4*)xr;
  for (int i = tid; i < 1024; i += 256) xr4[i] = xp4[i];
  __syncthreads();
  // phase A: thread (mi = tid&31, r = tid>>5) handles b = r+8k, k=0..7
  {
    int mi = tid & 31, r = tid >> 5;
    int m = mi - 15, mm = m & 63;
    float re[8], im[8];
#pragma unroll
    for (int k2 = 0; k2 < 8; k2++) { re[k2] = 0.f; im[k2] = 0.f; }
    int t = 0; // (m*a) & 63, exact incremental
    for (int a = 0; a < 64; a++) {
      float cw = lc[t], sw = ls[t];
#pragma unroll
      for (int k2 = 0; k2 < 8; k2++) {
        float v = xr[(r + 8 * k2) * 64 + a];
        re[k2] += v * cw;
        im[k2] -= v * sw;
      }
      t = (t + mm) & 63;
    }
    if (mi < 31) {
#pragma unroll
      for (int k2 = 0; k2 < 8; k2++)
        fz2[(r + 8 * k2) * 32 + mi] = make_float2(re[k2], im[k2]);
    }
  }
  __syncthreads();
  // phase C: z[lm] = sum_b WtT[b][lm] * xf[b][mi(lm)]
  {
    int lm = tid;
    int l = (int)sqrtf((float)lm + 0.5f);
    if (l * l > lm) l--;
    else if ((l + 1) * (l + 1) <= lm) l++;
    int miC = (lm - l * l) - l + 15;
    float zr = 0.f, zi = 0.f;
    for (int b = 0; b < 64; b++) {
      float wv = WtT[b * NLM + lm];
      float2 f = fz2[b * 32 + miC];
      zr += wv * f.x;
      zi += wv * f.y;
    }
    z_arr[(size_t)lm * 2048 + zf] = make_float2(zr, zi);
  }
}

// K2: y[lm][f][o] = sum_g (kernel[f][o][g]*S) * Y[g][lm].  One block per lm.
__global__ __launch_bounds__(256) void k_ybuild(const float* __restrict__ kern,
                                                const float* __restrict__ Yre,
                                                const float* __restrict__ Yim,
                                                float S, float2* __restrict__ y_arr) {
  __shared__ float yr[24], yi[24];
  int lm = blockIdx.x, tid = threadIdx.x;
  if (tid < 24) { yr[tid] = Yre[tid * NLM + lm]; yi[tid] = Yim[tid * NLM + lm]; }
  __syncthreads();
  for (int p = tid; p < 2048; p += 256) {
    const float* kp = kern + (size_t)p * 24;
    float re = 0.f, im = 0.f;
    for (int g = 0; g < 24; g++) {
      float kv = kp[g] * S;
      re += kv * yr[g];
      im += kv * yi[g];
    }
    y_arr[(size_t)lm * 2048 + p] = make_float2(re, im);
  }
}

// K3: per (l,m1,m2): num = sum_f z1*y2 (c64), den = Re sum_f conj(y1)*y2 (f64 acc),
//     Fz = num/den. One block per l-major pack. Writes Fz [pack][z32*o32] c64.
__global__ __launch_bounds__(256) void k_fz(const float2* __restrict__ z_arr,
                                            const float2* __restrict__ y_arr,
                                            float2* __restrict__ fz) {
  __shared__ __align__(16) float2 z1[2048];   // [zz][f]
  __shared__ __align__(16) float2 y1s[2048];  // [f][o]
  __shared__ __align__(16) float2 y2s[2048];  // [f][o]
  int pack = blockIdx.x, tid = threadIdx.x;
  int l = 15;
  while (d_off[l] > pack) l--;
  int rr = pack - d_off[l];
  int L = 2 * l + 1;
  int i1 = rr / L, i2 = rr - i1 * L;
  int lm1 = l * l + i1, lm2 = l * l + i2;
  for (int i = tid; i < 2048; i += 256) {
    z1[i]  = z_arr[(size_t)lm1 * 2048 + i];
    y1s[i] = y_arr[(size_t)lm1 * 2048 + i];
    y2s[i] = y_arr[(size_t)lm2 * 2048 + i];
  }
  __syncthreads();
  int zz = tid >> 3, oq = tid & 7; // 4 outputs: oo = 4*oq + 0..3
  float nr0 = 0.f, ni0 = 0.f, nr1 = 0.f, ni1 = 0.f;
  float nr2 = 0.f, ni2 = 0.f, nr3 = 0.f, ni3 = 0.f;
  double d0 = 0.0, d1 = 0.0, d2 = 0.0, d3 = 0.0;
  const float2* z1p = &z1[zz * 64];
  for (int f = 0; f < 64; f++) {
    float2 a = z1p[f];
    float2 c = y1s[f * 32 + zz];
    float4 b01 = *(const float4*)&y2s[f * 32 + 4 * oq];
    float4 b23 = *(const float4*)&y2s[f * 32 + 4 * oq + 2];
    nr0 += a.x * b01.x - a.y * b01.y;  ni0 += a.x * b01.y + a.y * b01.x;
    nr1 += a.x * b01.z - a.y * b01.w;  ni1 += a.x * b01.w + a.y * b01.z;
    nr2 += a.x * b23.x - a.y * b23.y;  ni2 += a.x * b23.y + a.y * b23.x;
    nr3 += a.x * b23.z - a.y * b23.w;  ni3 += a.x * b23.w + a.y * b23.z;
    d0 += (double)c.x * (double)b01.x + (double)c.y * (double)b01.y;
    d1 += (double)c.x * (double)b01.z + (double)c.y * (double)b01.w;
    d2 += (double)c.x * (double)b23.x + (double)c.y * (double)b23.y;
    d3 += (double)c.x * (double)b23.z + (double)c.y * (double)b23.w;
  }
  size_t base = (size_t)pack * 1024 + zz * 32 + 4 * oq;
  fz[base + 0] = make_float2(nr0 / (float)d0, ni0 / (float)d0);
  fz[base + 1] = make_float2(nr1 / (float)d1, ni1 / (float)d1);
  fz[base + 2] = make_float2(nr2 / (float)d2, ni2 / (float)d2);
  fz[base + 3] = make_float2(nr3 / (float)d3, ni3 / (float)d3);
}

// K4: permuting transpose: xt[zo][q] = fz[qmap[q]][zo]   (both c64), tiled.
__global__ __launch_bounds__(256) void k_tr(const float2* __restrict__ fz,
                                            const int* __restrict__ qmap,
                                            float2* __restrict__ xt) {
  __shared__ float2 tile[32][33];
  __shared__ int qm[32];
  int zo0 = blockIdx.x * 32;  // 0..1023
  int q0 = blockIdx.y * 32;   // 0..5455
  int tid = threadIdx.x;
  int c = tid & 31, r0 = tid >> 5;
  if (tid < 32) qm[tid] = (q0 + tid < NPACK) ? qmap[q0 + tid] : -1;
  __syncthreads();
  for (int r = r0; r < 32; r += 8) {
    int p = qm[r];
    if (p >= 0) tile[r][c] = fz[(size_t)p * 1024 + zo0 + c];
  }
  __syncthreads();
  for (int r = r0; r < 32; r += 8) {
    if (q0 + c < NPACK)
      xt[(size_t)(zo0 + r) * NPACK + q0 + c] = tile[c][r];
  }
}

// K5: synthesis. Grid 2048: zo = bx>>1, 16 b per block. X staged ONCE in LDS
// (43.6 KB coalesced) -- zero global re-reads across the 16 b iterations.
// Per b: F[mi,ni] = sum_l X*D (LDS X, L1-hot Dp gather);
// stage1 with kk-folding (w * i^{s(ni-15)}): 4 k-outputs per F-read;
// stage2 with j-folding: 4 real outputs per G-read.
__global__ __launch_bounds__(256, 2) void k_synth(const float2* __restrict__ xt,
                                                  const float* __restrict__ Dp,
                                                  const int* __restrict__ mn_off,
                                                  const float* __restrict__ gc32,
                                                  const float* __restrict__ gs32,
                                                  const float* __restrict__ bias,
                                                  float* __restrict__ out) {
  __shared__ __align__(16) float2 Xs[NPACK];      // 43648 B
  __shared__ __align__(16) float2 F2T[31 * 33];   // [ni][mi] stride 33 (8184 B)
  __shared__ __align__(16) float2 G2[31 * 33];    // [mi][kk] stride 33 (8184 B)
  __shared__ __align__(16) float2 tw2[8 * 31];    // [kp][ni], kp=0..7 (1984 B)
  int bx = blockIdx.x, tid = threadIdx.x;
  int zo = bx >> 1;
  int b0 = (bx & 1) * 16, b1 = b0 + 16;

  // stage X row into LDS (coalesced float4)
  {
    const float4* Xg = (const float4*)(xt + (size_t)zo * NPACK);
    float4* Xl = (float4*)Xs;
    for (int i = tid; i < NPACK / 2; i += 256) Xl[i] = Xg[i];
  }
  // exact twiddles, kp = 0..7 only (folding covers +8,+16,+24)
  if (tid < 248) {
    int kp = tid / 31, nq = tid - kp * 31;
    int p = (kp * (nq - 15)) & 31;
    tw2[tid] = make_float2(gc32[p], gs32[p]);
  }
  // per-thread F-build slots: t = tid + 256*s over 961 (m,n) pairs
  int xb[4], ln[4], wo[4];
#pragma unroll
  for (int s = 0; s < 4; s++) {
    int t = tid + 256 * s;
    if (t < NMN) {
      int mi = t / 31, ni = t - 31 * mi;
      int m = mi - 15, n = ni - 15;
      int am = m < 0 ? -m : m, an = n < 0 ? -n : n;
      int lmin = am > an ? am : an;
      xb[s] = mn_off[t];
      ln[s] = 16 - lmin;
      wo[s] = ni * 33 + mi;
    } else {
      xb[s] = 0; ln[s] = 0; wo[s] = 0;
    }
  }
  float bv = bias[zo & 31];
  int kk8 = tid >> 5;      // stage1: k base 0..7
  int c31 = tid & 31;      // stage1: mi (31 -> idle)
  int kk = tid & 31;       // stage2: k column
  int row = tid >> 5;      // stage2: j base 0..7
  __syncthreads();

  // F-build for first b
  {
    const float* Db = Dp + (size_t)b0 * NPACK;
#pragma unroll
    for (int s = 0; s < 4; s++) {
      int L = ln[s];
      if (L > 0) {
        const float2* xp = Xs + xb[s];
        const float* dp = Db + xb[s];
        float fr = 0.f, fi = 0.f;
        for (int li = 0; li < L; li++) {
          float2 xv = xp[li];
          float dv = dp[li];
          fr += xv.x * dv;
          fi += xv.y * dv;
        }
        F2T[wo[s]] = make_float2(fr, fi);
      }
    }
  }
  __syncthreads();

#pragma unroll 1
  for (int b = b0; b < b1; b++) {
    // ---- stage 1: G[mi, kk8+8s] = sum_ni F[mi,ni] * w(kk8,ni) * i^{s(ni-15)}
    {
      float2 g0 = make_float2(0.f, 0.f), g1 = make_float2(0.f, 0.f);
      float2 g2 = make_float2(0.f, 0.f), g3 = make_float2(0.f, 0.f);
      if (c31 < 31) {
#pragma unroll
        for (int ni = 0; ni < 31; ni++) {
          float2 f = F2T[ni * 33 + c31];
          float2 w = tw2[kk8 * 31 + ni];
          float u = f.x * w.x - f.y * w.y;
          float v = f.x * w.y + f.y * w.x;
          int p1 = (ni - 15) & 3;            // compile-time after unroll
          int p2 = (2 * (ni - 15)) & 3;      // in {0,2}
          int p3 = (3 * (ni - 15)) & 3;
          g0.x += u;                          g0.y += v;
          g1.x += (p1 == 0) ? u : (p1 == 1) ? -v : (p1 == 2) ? -u : v;
          g1.y += (p1 == 0) ? v : (p1 == 1) ?  u : (p1 == 2) ? -v : -u;
          g2.x += (p2 == 0) ? u : -u;
          g2.y += (p2 == 0) ? v : -v;
          g3.x += (p3 == 0) ? u : (p3 == 1) ? -v : (p3 == 2) ? -u : v;
          g3.y += (p3 == 0) ? v : (p3 == 1) ?  u : (p3 == 2) ? -v : -u;
        }
        G2[c31 * 33 + kk8]      = g0;
        G2[c31 * 33 + kk8 + 8]  = g1;
        G2[c31 * 33 + kk8 + 16] = g2;
        G2[c31 * 33 + kk8 + 24] = g3;
      }
    }
    __syncthreads();

    // ---- F-build for next b (overlaps stage 2; different LDS buffer)
    if (b + 1 < b1) {
      const float* Db = Dp + (size_t)(b + 1) * NPACK;
#pragma unroll
      for (int s = 0; s < 4; s++) {
        int L = ln[s];
        if (L > 0) {
          const float2* xp = Xs + xb[s];
          const float* dp = Db + xb[s];
          float fr = 0.f, fi = 0.f;
          for (int li = 0; li < L; li++) {
            float2 xv = xp[li];
            float dv = dp[li];
            fr += xv.x * dv;
            fi += xv.y * dv;
          }
          F2T[wo[s]] = make_float2(fr, fi);
        }
      }
    }

    // ---- stage 2: out[row+8s, kk] = Re sum_mi G[mi,kk] * w(row,mi) * i^{s(mi-15)}
    {
      float a0 = 0.f, a1 = 0.f, a2 = 0.f, a3 = 0.f;
#pragma unroll
      for (int mi = 0; mi < 31; mi++) {
        float2 g = G2[mi * 33 + kk];
        float2 w = tw2[row * 31 + mi];
        float u = g.x * w.x - g.y * w.y;
        float v = g.x * w.y + g.y * w.x;
        int p1 = (mi - 15) & 3;
        int p2 = (2 * (mi - 15)) & 3;
        int p3 = (3 * (mi - 15)) & 3;
        a0 += u;
        a1 += (p1 == 0) ? u : (p1 == 1) ? -v : (p1 == 2) ? -u : v;
        a2 += (p2 == 0) ? u : -u;
        a3 += (p3 == 0) ? u : (p3 == 1) ? -v : (p3 == 2) ? -u : v;
      }
      size_t base = (size_t)zo * 32768 + (size_t)b * 1024 + kk;
      out[base + (row + 0) * 32]  = a0 + bv;
      out[base + (row + 8) * 32]  = a1 + bv;
      out[base + (row + 16) * 32] = a2 + bv;
      out[base + (row + 24) * 32] = a3 + bv;
    }
    __syncthreads();
  }
}

// ---------------- launch ----------------
static Tables* g_htbl = nullptr;
static std::once_flag g_once;

static constexpr size_t align256(size_t v) { return (v + 255) & ~(size_t)255; }
static constexpr size_t WS_TBL = 0;
static constexpr size_t WS_Z   = align256(sizeof(Tables));
static constexpr size_t WS_Y   = WS_Z + (size_t)NLM * 2048 * 8;
static constexpr size_t WS_FZ  = WS_Y + (size_t)NLM * 2048 * 8;
static constexpr size_t WS_XT  = WS_FZ + (size_t)NPACK * 1024 * 8;

extern "C" void kernel_launch(void* const* d_in, const int* in_sizes, int n_in,
                              void* d_out, int out_size, void* d_ws, size_t ws_size,
                              hipStream_t stream) {
  std::call_once(g_once, [] {
    hipHostMalloc((void**)&g_htbl, sizeof(Tables));
    build_tables(*g_htbl);
  });

  const float* x = (const float*)d_in[0];
  const float* kern = (const float*)d_in[1];
  const float* bias = (const float*)d_in[2];
  float* out = (float*)d_out;
  char* ws = (char*)d_ws;

  hipMemcpyAsync(ws + WS_TBL, g_htbl, sizeof(Tables), hipMemcpyHostToDevice, stream);

  Tables* dT = (Tables*)(ws + WS_TBL);
  float2* z_arr = (float2*)(ws + WS_Z);
  float2* y_arr = (float2*)(ws + WS_Y);
  float2* fzb   = (float2*)(ws + WS_FZ);
  float2* xtb   = (float2*)(ws + WS_XT);

  float S = (float)(1.0 / std::sqrt(24.0 * 64.0 * 65536.0 / 1024.0));

  k_zbuild<<<2048, 256, 0, stream>>>(x, dT->WtT, dT->c64, dT->s64, z_arr);
  k_ybuild<<<256, 256, 0, stream>>>(kern, dT->Yre, dT->Yim, S, y_arr);
  k_fz<<<NPACK, 256, 0, stream>>>(z_arr, y_arr, fzb);
  k_tr<<<dim3(32, 171), 256, 0, stream>>>(fzb, dT->qmap, xtb);
  k_synth<<<2048, 256, 0, stream>>>(xtb, dT->Dp, dT->mn_off, dT->c32, dT->s32, bias, out);
}